// Round 1
// baseline (266.333 us; speedup 1.0000x reference)
//
#include <hip/hip_runtime.h>
#include <hip/hip_bf16.h>

#define E_MSGS 131072
#define N_NODES 8192
#define D_DIM 256
#define XA_STRIDE 264  // 256 + 8 bf16 pad for A-frag ds_read_b128

typedef __bf16 bf16x8 __attribute__((ext_vector_type(8)));
typedef float f32x4 __attribute__((ext_vector_type(4)));

// raw workgroup barrier: drains LDS (lgkm) only — vmem prefetch stays in flight
#define BAR() asm volatile("s_waitcnt lgkmcnt(0)\n\ts_barrier" ::: "memory")

// ================= phase 1: counting sort (lean) =================

__global__ void k_count(const int* __restrict__ index, int* __restrict__ counts) {
    int e = blockIdx.x * blockDim.x + threadIdx.x;
    if (e < E_MSGS) atomicAdd(&counts[index[e]], 1);
}

// 1 block x 1024 threads: exclusive scan counts->offsets, zero cursors.
// (No count-sort perm: with all 512 gru blocks co-resident, makespan = S_max
//  regardless of grouping, so the histogram/perm machinery is dead weight.)
__global__ void k_scan(const int* __restrict__ counts, int* __restrict__ offsets,
                       int* __restrict__ cursors) {
    __shared__ int wsum[16], wpre[16];
    int tid = threadIdx.x, lane = tid & 63, wave = tid >> 6;
    int base = tid * 8;
    int4 c0 = *(const int4*)(counts + base);
    int4 c1 = *(const int4*)(counts + base + 4);
    int v[8] = {c0.x, c0.y, c0.z, c0.w, c1.x, c1.y, c1.z, c1.w};
    int loc[8], sum = 0;
#pragma unroll
    for (int i = 0; i < 8; i++) { loc[i] = sum; sum += v[i]; }
    int incl = sum;
#pragma unroll
    for (int d = 1; d < 64; d <<= 1) {
        int u = __shfl_up(incl, d);
        if (lane >= d) incl += u;
    }
    if (lane == 63) wsum[wave] = incl;
    __syncthreads();
    if (tid < 16) {
        int w = wsum[tid], p = w;
#pragma unroll
        for (int d = 1; d < 16; d <<= 1) {
            int u = __shfl_up(p, d);
            if (tid >= d) p += u;
        }
        wpre[tid] = p - w;  // exclusive wave prefix
    }
    __syncthreads();
    int ebase = wpre[wave] + incl - sum;  // global exclusive prefix of this thread
#pragma unroll
    for (int i = 0; i < 8; i++) offsets[base + i] = ebase + loc[i];
    int4 z = {0, 0, 0, 0};
    *(int4*)(cursors + base) = z;
    *(int4*)(cursors + base + 4) = z;
    if (tid == 0) offsets[N_NODES] = E_MSGS;
}

__global__ void k_scatter(const int* __restrict__ index, const int* __restrict__ offsets,
                          int* __restrict__ cursors, int* __restrict__ bucket) {
    int e = blockIdx.x * blockDim.x + threadIdx.x;
    if (e < E_MSGS) {
        int n = index[e];
        int p = offsets[n] + atomicAdd(&cursors[n], 1);
        bucket[p] = e;
    }
}

// ================= phase 2: serial recurrence =================
// 16 nodes/block (identity perm). Segment sort fused in-block (wave shuffle
// rank sort, sorted ids -> LDS). Per-step addresses come from LDS (ds_read),
// so the only per-step vmem is the 16 msg prefetch loads -> counted vmcnt,
// no per-step full drain. Step body is a macro (static indexing, no lambda).

#define GRU_STEP(SS, CUR, NXT)                                                 \
    {                                                                          \
        _Pragma("unroll") for (int r = 0; r < 4; r++) {                        \
            const float* mrow = msg + (long)sidR[r] * D_DIM;                   \
            _Pragma("unroll") for (int t4 = 0; t4 < 4; t4++)                   \
                NXT[r][t4] = mrow[64 * wave + 16 * t4 + l];                     \
        }                                                                      \
        {                                                                      \
            int row = (SS) + 3 < 64 ? (SS) + 3 : 63;                           \
            int4 sr = *(const int4*)&sid[row][4 * q];                          \
            sidR[0] = sr.x; sidR[1] = sr.y; sidR[2] = sr.z; sidR[3] = sr.w;    \
        }                                                                      \
        const __bf16* buf = xA[(SS) & 1];                                      \
        f32x4 acc[4];                                                          \
        _Pragma("unroll") for (int t4 = 0; t4 < 4; t4++)                       \
            acc[t4] = (f32x4){0.f, 0.f, 0.f, 0.f};                             \
        _Pragma("unroll") for (int c = 0; c < 8; c++) {                        \
            bf16x8 a = *(const bf16x8*)(buf + l * XA_STRIDE + 32 * c + 8 * q); \
            _Pragma("unroll") for (int t4 = 0; t4 < 4; t4++)                   \
                acc[t4] = __builtin_amdgcn_mfma_f32_16x16x32_bf16(             \
                    a, wf[c][t4], acc[t4], 0, 0, 0);                           \
        }                                                                      \
        __bf16* nbuf = xA[((SS) + 1) & 1];                                     \
        _Pragma("unroll") for (int t4 = 0; t4 < 4; t4++) {                     \
            _Pragma("unroll") for (int r = 0; r < 4; r++) {                    \
                float hn = acc[t4][r] + bias[t4];                              \
                bool valid = (SS) < cnt4[r];                                   \
                h[t4][r] = valid ? hn : h[t4][r];                              \
                nbuf[(4 * q + r) * XA_STRIDE + 64 * wave + 16 * t4 + l] =      \
                    (__bf16)(h[t4][r] + CUR[r][t4]);                           \
            }                                                                  \
        }                                                                      \
        BAR();                                                                 \
    }

__launch_bounds__(256, 2)
__global__ void k_gru(const float* __restrict__ msg, const float* __restrict__ t,
                      const int* __restrict__ bucket, const float* __restrict__ W,
                      const float* __restrict__ b, const int* __restrict__ offsets,
                      float* __restrict__ out) {
    __shared__ __bf16 xA[2][16 * XA_STRIDE];
    __shared__ int sid[64][16];  // sorted msg ids per node column; rows>=cnt are 0

    int tid = threadIdx.x;
    int wave = tid >> 6, lane = tid & 63, q = lane >> 4, l = lane & 15;
    int node0 = blockIdx.x * 16;

    // ---- W fragments (B operand: B[k][n]=W[n][k]; lane n=64w+16t4+l, k=32c+8q+j) ----
    bf16x8 wf[8][4];
#pragma unroll
    for (int t4 = 0; t4 < 4; t4++) {
        const float* wr = W + (64 * wave + 16 * t4 + l) * D_DIM;
#pragma unroll
        for (int c = 0; c < 8; c++) {
            int k0 = 32 * c + 8 * q;
            float4 w0 = *(const float4*)(wr + k0);
            float4 w1 = *(const float4*)(wr + k0 + 4);
            bf16x8 f;
            f[0] = (__bf16)w0.x; f[1] = (__bf16)w0.y; f[2] = (__bf16)w0.z; f[3] = (__bf16)w0.w;
            f[4] = (__bf16)w1.x; f[5] = (__bf16)w1.y; f[6] = (__bf16)w1.z; f[7] = (__bf16)w1.w;
            wf[c][t4] = f;
        }
    }
    float bias[4];
#pragma unroll
    for (int t4 = 0; t4 < 4; t4++) bias[t4] = b[64 * wave + 16 * t4 + l];

    // quad q owns C/D rows 4q+r (nodes node0+4q+r)
    int off4[4], cnt4[4];
#pragma unroll
    for (int r = 0; r < 4; r++) {
        off4[r] = offsets[node0 + 4 * q + r];
        cnt4[r] = offsets[node0 + 4 * q + r + 1] - off4[r];
    }
    // block-max count = step count S (wave-uniform; same nodes in every wave)
    int mc = max(max(cnt4[0], cnt4[1]), max(cnt4[2], cnt4[3]));
    mc = max(mc, __shfl_xor(mc, 16));
    mc = max(mc, __shfl_xor(mc, 32));
    int S = mc;

    // ---- in-block segment sort: wave w sorts nodes 4w..4w+3 (cnt<=64) ----
    for (int i = 0; i < 4; i++) {
        int j = 4 * wave + i;
        int beg = offsets[node0 + j];
        int cnt = min(offsets[node0 + j + 1] - beg, 64);
        sid[lane][j] = 0;  // zero column so rows>=cnt give a safe msg row 0
        int e = 0; float tv = 0.f;
        if (lane < cnt) { e = bucket[beg + lane]; tv = t[e]; }
        int rank = 0;
        for (int j2 = 0; j2 < cnt; j2++) {
            float tj = __shfl(tv, j2);
            int ej = __shfl(e, j2);
            rank += (tj < tv) || (tj == tv && ej < e);
        }
        if (lane < cnt) sid[rank][j] = e;
    }
    BAR();  // sid visible to all waves

    // ---- prologue: x_0 = m_0 -> xA[0]; mvA = m_1; sidR = sid[2] ----
    float h[4][4];
#pragma unroll
    for (int t4 = 0; t4 < 4; t4++)
#pragma unroll
        for (int r = 0; r < 4; r++) h[t4][r] = 0.f;

    float mvA[4][4], mvB[4][4];
    int sidR[4];
    int4 sr0 = *(const int4*)&sid[0][4 * q];
    int4 sr1 = *(const int4*)&sid[1][4 * q];
    int4 sr2 = *(const int4*)&sid[2][4 * q];
    int s0[4] = {sr0.x, sr0.y, sr0.z, sr0.w};
    int s1[4] = {sr1.x, sr1.y, sr1.z, sr1.w};
    sidR[0] = sr2.x; sidR[1] = sr2.y; sidR[2] = sr2.z; sidR[3] = sr2.w;
#pragma unroll
    for (int r = 0; r < 4; r++) {
        const float* m0 = msg + (long)s0[r] * D_DIM;
        const float* m1 = msg + (long)s1[r] * D_DIM;
#pragma unroll
        for (int t4 = 0; t4 < 4; t4++) {
            int col = 64 * wave + 16 * t4 + l;
            xA[0][(4 * q + r) * XA_STRIDE + col] = (__bf16)m0[col];
            mvA[r][t4] = m1[col];
        }
    }
    BAR();

    int s = 0;
    while (s < S) {
        GRU_STEP(s, mvA, mvB); s++;
        if (s >= S) break;
        GRU_STEP(s, mvB, mvA); s++;
    }

    // ---- write fp32 h (0 for empty nodes) ----
#pragma unroll
    for (int t4 = 0; t4 < 4; t4++)
#pragma unroll
        for (int r = 0; r < 4; r++)
            out[(long)(node0 + 4 * q + r) * D_DIM + 64 * wave + 16 * t4 + l] = h[t4][r];
}

// ================= launch =================

extern "C" void kernel_launch(void* const* d_in, const int* in_sizes, int n_in,
                              void* d_out, int out_size, void* d_ws, size_t ws_size,
                              hipStream_t stream) {
    const float* msg   = (const float*)d_in[0];
    const int*   index = (const int*)d_in[1];
    const float* t     = (const float*)d_in[2];
    const float* W     = (const float*)d_in[4];
    const float* b     = (const float*)d_in[5];
    float* out = (float*)d_out;

    int* ws = (int*)d_ws;
    int* counts  = ws;            // [8192]
    int* cursors = ws + 8192;     // [8192]  (zeroed by k_scan)
    int* offsets = ws + 16384;    // [8193]
    int* bucket  = ws + 24584;    // [131072]

    hipMemsetAsync(counts, 0, 8192 * sizeof(int), stream);

    k_count<<<E_MSGS / 256, 256, 0, stream>>>(index, counts);
    k_scan<<<1, 1024, 0, stream>>>(counts, offsets, cursors);
    k_scatter<<<E_MSGS / 256, 256, 0, stream>>>(index, offsets, cursors, bucket);
    k_gru<<<N_NODES / 16, 256, 0, stream>>>(msg, t, bucket, W, b, offsets, out);
}

// Round 2
// 263.531 us; speedup vs baseline: 1.0106x; 1.0106x over previous
//
#include <hip/hip_runtime.h>
#include <hip/hip_bf16.h>

#define E_MSGS 131072
#define N_NODES 8192
#define D_DIM 256
#define XA_STRIDE 264  // 256 + 8 bf16 pad for A-frag ds_read_b128

typedef __bf16 bf16x8 __attribute__((ext_vector_type(8)));
typedef float f32x4 __attribute__((ext_vector_type(4)));

// raw workgroup barrier: drains LDS (lgkm) only — vmem prefetch stays in flight
#define BAR() asm volatile("s_waitcnt lgkmcnt(0)\n\ts_barrier" ::: "memory")

// ============ phase 1: padded-bucket scatter (replaces count+scan+scatter) ======
// pad[n*64 + p] = message id; cursors[n] ends as count[n]. No offsets needed.

__global__ void k_scatter(const int* __restrict__ index, int* __restrict__ cursors,
                          int* __restrict__ pad) {
    int e = blockIdx.x * blockDim.x + threadIdx.x;
    int n = index[e];
    int p = atomicAdd(&cursors[n], 1);
    if (p < 64) pad[(n << 6) + p] = e;
}

// one block: count-desc node permutation. Grouping nodes of similar count into
// the same 16-node block minimizes Sigma_b S_b (total masked step work) — the
// quantity that governs makespan when co-resident blocks' latency chains
// serialize (round-1 lesson: ungrouped cost exactly the predicted 1.3x more).
__global__ void k_perm(const int* __restrict__ counts, int* __restrict__ perm) {
    __shared__ int hist[65];
    __shared__ int hcur[65];
    int tid = threadIdx.x;
    if (tid < 65) hist[tid] = 0;
    __syncthreads();
    int myc[32];
#pragma unroll
    for (int i = 0; i < 32; i++) {
        int c = min(counts[tid * 32 + i], 64);
        myc[i] = c;
        atomicAdd(&hist[c], 1);
    }
    __syncthreads();
    if (tid == 0) {  // serial 65-bin descending exclusive scan (~65 LDS ops)
        int run = 0;
        for (int c = 64; c >= 0; c--) { hcur[c] = run; run += hist[c]; }
    }
    __syncthreads();
#pragma unroll
    for (int i = 0; i < 32; i++) {
        int pos = atomicAdd(&hcur[myc[i]], 1);
        perm[pos] = tid * 32 + i;
    }
}

// ================= phase 2: serial recurrence =================
// 16 count-grouped nodes/block. In-block segment sort (wave shuffle rank sort,
// sorted ids -> LDS sid). Per-step addresses come from LDS (ds_read), so the
// only per-step vmem is the 16 msg prefetch loads (register prefetch, distance
// 2) — never drained by the lgkm-only barrier. Step body = macro (static idx).

#define GRU_STEP(SS, CUR, NXT)                                                 \
    {                                                                          \
        _Pragma("unroll") for (int r = 0; r < 4; r++) {                        \
            const float* mrow = msg + (long)sidR[r] * D_DIM;                   \
            _Pragma("unroll") for (int t4 = 0; t4 < 4; t4++)                   \
                NXT[r][t4] = mrow[64 * wave + 16 * t4 + l];                     \
        }                                                                      \
        {                                                                      \
            int row = (SS) + 3 < 64 ? (SS) + 3 : 63;                           \
            int4 sr = *(const int4*)&sid[row][4 * q];                          \
            sidR[0] = sr.x; sidR[1] = sr.y; sidR[2] = sr.z; sidR[3] = sr.w;    \
        }                                                                      \
        const __bf16* buf = xA[(SS) & 1];                                      \
        f32x4 acc[4];                                                          \
        _Pragma("unroll") for (int t4 = 0; t4 < 4; t4++)                       \
            acc[t4] = (f32x4){0.f, 0.f, 0.f, 0.f};                             \
        __builtin_amdgcn_s_setprio(1);                                         \
        _Pragma("unroll") for (int c = 0; c < 8; c++) {                        \
            bf16x8 a = *(const bf16x8*)(buf + l * XA_STRIDE + 32 * c + 8 * q); \
            _Pragma("unroll") for (int t4 = 0; t4 < 4; t4++)                   \
                acc[t4] = __builtin_amdgcn_mfma_f32_16x16x32_bf16(             \
                    a, wf[c][t4], acc[t4], 0, 0, 0);                           \
        }                                                                      \
        __builtin_amdgcn_s_setprio(0);                                         \
        __bf16* nbuf = xA[((SS) + 1) & 1];                                     \
        _Pragma("unroll") for (int t4 = 0; t4 < 4; t4++) {                     \
            _Pragma("unroll") for (int r = 0; r < 4; r++) {                    \
                float hn = acc[t4][r] + bias[t4];                              \
                bool valid = (SS) < cnt4[r];                                   \
                h[t4][r] = valid ? hn : h[t4][r];                              \
                nbuf[(4 * q + r) * XA_STRIDE + 64 * wave + 16 * t4 + l] =      \
                    (__bf16)(h[t4][r] + CUR[r][t4]);                           \
            }                                                                  \
        }                                                                      \
        BAR();                                                                 \
    }

__launch_bounds__(256, 2)
__global__ void k_gru(const float* __restrict__ msg, const float* __restrict__ t,
                      const int* __restrict__ pad, const float* __restrict__ W,
                      const float* __restrict__ b, const int* __restrict__ counts,
                      const int* __restrict__ perm, float* __restrict__ out) {
    __shared__ __bf16 xA[2][16 * XA_STRIDE];
    __shared__ int sid[64][16];  // sorted msg ids per node column; rows>=cnt are 0

    int tid = threadIdx.x;
    int wave = tid >> 6, lane = tid & 63, q = lane >> 4, l = lane & 15;
    int node0 = blockIdx.x * 16;

    // ---- W fragments (B operand: B[k][n]=W[n][k]; lane n=64w+16t4+l, k=32c+8q+j) ----
    bf16x8 wf[8][4];
#pragma unroll
    for (int t4 = 0; t4 < 4; t4++) {
        const float* wr = W + (64 * wave + 16 * t4 + l) * D_DIM;
#pragma unroll
        for (int c = 0; c < 8; c++) {
            int k0 = 32 * c + 8 * q;
            float4 w0 = *(const float4*)(wr + k0);
            float4 w1 = *(const float4*)(wr + k0 + 4);
            bf16x8 f;
            f[0] = (__bf16)w0.x; f[1] = (__bf16)w0.y; f[2] = (__bf16)w0.z; f[3] = (__bf16)w0.w;
            f[4] = (__bf16)w1.x; f[5] = (__bf16)w1.y; f[6] = (__bf16)w1.z; f[7] = (__bf16)w1.w;
            wf[c][t4] = f;
        }
    }
    float bias[4];
#pragma unroll
    for (int t4 = 0; t4 < 4; t4++) bias[t4] = b[64 * wave + 16 * t4 + l];

    // quad q owns C/D rows 4q+r -> nodes perm[node0+4q+r]
    int nodeC[4], cnt4[4];
#pragma unroll
    for (int r = 0; r < 4; r++) {
        int n = perm[node0 + 4 * q + r];
        nodeC[r] = n;
        cnt4[r] = min(counts[n], 64);
    }
    // count-desc perm: first node of the block has the block-max count
    int S = min(counts[perm[node0]], 64);

    // ---- in-block segment sort: wave w sorts nodes j=4w..4w+3 (cnt<=64) ----
    for (int i = 0; i < 4; i++) {
        int j = 4 * wave + i;
        int n = perm[node0 + j];
        int cnt = min(counts[n], 64);
        sid[lane][j] = 0;  // rows>=cnt give msg row 0 (safe, cached)
        int e = 0; float tv = 0.f;
        if (lane < cnt) { e = pad[(n << 6) + lane]; tv = t[e]; }
        int rank = 0;
        for (int j2 = 0; j2 < cnt; j2++) {
            float tj = __shfl(tv, j2);
            int ej = __shfl(e, j2);
            rank += (tj < tv) || (tj == tv && ej < e);  // stable: tie -> orig id
        }
        if (lane < cnt) sid[rank][j] = e;
    }
    BAR();  // sid visible to all waves

    // ---- prologue: x_0 = m_0 -> xA[0]; mvA = m_1; sidR = sid[2] ----
    float h[4][4];
#pragma unroll
    for (int t4 = 0; t4 < 4; t4++)
#pragma unroll
        for (int r = 0; r < 4; r++) h[t4][r] = 0.f;

    float mvA[4][4], mvB[4][4];
    int sidR[4];
    int4 sr0 = *(const int4*)&sid[0][4 * q];
    int4 sr1 = *(const int4*)&sid[1][4 * q];
    int4 sr2 = *(const int4*)&sid[2][4 * q];
    int s0[4] = {sr0.x, sr0.y, sr0.z, sr0.w};
    int s1[4] = {sr1.x, sr1.y, sr1.z, sr1.w};
    sidR[0] = sr2.x; sidR[1] = sr2.y; sidR[2] = sr2.z; sidR[3] = sr2.w;
#pragma unroll
    for (int r = 0; r < 4; r++) {
        const float* m0 = msg + (long)s0[r] * D_DIM;
        const float* m1 = msg + (long)s1[r] * D_DIM;
#pragma unroll
        for (int t4 = 0; t4 < 4; t4++) {
            int col = 64 * wave + 16 * t4 + l;
            xA[0][(4 * q + r) * XA_STRIDE + col] = (__bf16)m0[col];
            mvA[r][t4] = m1[col];
        }
    }
    BAR();

    int s = 0;
    while (s < S) {
        GRU_STEP(s, mvA, mvB); s++;
        if (s >= S) break;
        GRU_STEP(s, mvB, mvA); s++;
    }

    // ---- write fp32 h (0 for empty nodes) ----
#pragma unroll
    for (int t4 = 0; t4 < 4; t4++)
#pragma unroll
        for (int r = 0; r < 4; r++)
            out[(long)nodeC[r] * D_DIM + 64 * wave + 16 * t4 + l] = h[t4][r];
}

// ================= launch =================

extern "C" void kernel_launch(void* const* d_in, const int* in_sizes, int n_in,
                              void* d_out, int out_size, void* d_ws, size_t ws_size,
                              hipStream_t stream) {
    const float* msg   = (const float*)d_in[0];
    const int*   index = (const int*)d_in[1];
    const float* t     = (const float*)d_in[2];
    const float* W     = (const float*)d_in[4];
    const float* b     = (const float*)d_in[5];
    float* out = (float*)d_out;

    int* ws = (int*)d_ws;
    int* cursors = ws;            // [8192] -> ends as counts
    int* perm    = ws + 8192;     // [8192]
    int* pad     = ws + 16384;    // [8192*64]

    hipMemsetAsync(cursors, 0, 8192 * sizeof(int), stream);

    k_scatter<<<E_MSGS / 256, 256, 0, stream>>>(index, cursors, pad);
    k_perm<<<1, 256, 0, stream>>>(cursors, perm);
    k_gru<<<N_NODES / 16, 256, 0, stream>>>(msg, t, pad, W, b, cursors, perm, out);
}

// Round 3
// 250.410 us; speedup vs baseline: 1.0636x; 1.0524x over previous
//
#include <hip/hip_runtime.h>
#include <hip/hip_bf16.h>

#define E_MSGS 131072
#define N_NODES 8192
#define D_DIM 256
#define XA_STRIDE 264  // 256 + 8 bf16 pad for A-frag ds_read_b128

typedef __bf16 bf16x8 __attribute__((ext_vector_type(8)));
typedef float f32x4 __attribute__((ext_vector_type(4)));

// raw workgroup barrier: drains LDS (lgkm) only — vmem prefetch stays in flight
#define BAR() asm volatile("s_waitcnt lgkmcnt(0)\n\ts_barrier" ::: "memory")

// ============ phase 1: padded-bucket scatter + grouping + in-place sort ========
// pad[n*64+p] = msg id (memset 0 first, so rows >= cnt are 0 = safe msg row).
// cursors[n] ends as count[n]. No offsets array anywhere.

__global__ void k_scatter(const int* __restrict__ index, int* __restrict__ cursors,
                          int* __restrict__ pad) {
    int e = blockIdx.x * blockDim.x + threadIdx.x;
    int n = index[e];
    int p = atomicAdd(&cursors[n], 1);
    if (p < 64) pad[(n << 6) + p] = e;
}

// one block: count-desc node permutation (round-0-proven grouping; cheap).
__global__ void k_perm(const int* __restrict__ counts, int* __restrict__ perm) {
    __shared__ int hist[65];
    __shared__ int hcur[65];
    int tid = threadIdx.x;
    if (tid < 65) hist[tid] = 0;
    __syncthreads();
    int myc[32];
#pragma unroll
    for (int i = 0; i < 32; i++) {
        int c = min(counts[tid * 32 + i], 64);
        myc[i] = c;
        atomicAdd(&hist[c], 1);
    }
    __syncthreads();
    if (tid == 0) {
        int run = 0;
        for (int c = 64; c >= 0; c--) { hcur[c] = run; run += hist[c]; }
    }
    __syncthreads();
#pragma unroll
    for (int i = 0; i < 32; i++) {
        int pos = atomicAdd(&hcur[myc[i]], 1);
        perm[pos] = tid * 32 + i;
    }
}

// one wave per node: rank-sort pad row by (t asc, id asc) IN PLACE (cnt<=64).
// Safe: all lane reads (one instr) retire before the write instr issues.
__global__ void k_sortseg(const float* __restrict__ t, const int* __restrict__ counts,
                          int* __restrict__ pad) {
    int wid = (blockIdx.x * 256 + threadIdx.x) >> 6;
    int ln = threadIdx.x & 63;
    int cnt = min(counts[wid], 64);
    int base = wid << 6;
    int e = 0; float tv = 0.f;
    if (ln < cnt) { e = pad[base + ln]; tv = t[e]; }
    int rank = 0;
    for (int j = 0; j < cnt; j++) {
        float tj = __shfl(tv, j);
        int ej = __shfl(e, j);
        rank += (tj < tv) || (tj == tv && ej < e);  // stable: tie -> orig id
    }
    if (ln < cnt) pad[base + rank] = e;
}

// ================= phase 2: serial recurrence (round-0 structure, 8 waves) =====
// 16 count-grouped nodes/block, 512 threads: 8 waves x 32 out-dims each.
// wf = 64 VGPR/wave -> ~128 total -> 2 blocks/CU = 16 waves/CU (2x round 0's
// occupancy; the counters showed 17% occupancy with every latency exposed).
// Step structure identical to the proven 80us round-0 kernel: register msg
// prefetch distance 2, global sid prefetch distance 3, lgkm-only barrier.

__launch_bounds__(512, 4)
__global__ void k_gru(const float* __restrict__ msg, const float* __restrict__ W,
                      const float* __restrict__ b, const int* __restrict__ counts,
                      const int* __restrict__ spad, const int* __restrict__ perm,
                      float* __restrict__ out) {
    __shared__ __bf16 xA[2][16 * XA_STRIDE];

    int tid  = threadIdx.x;
    int wave = tid >> 6;   // 0..7
    int lane = tid & 63;
    int q    = lane >> 4;
    int l    = lane & 15;
    int node0 = blockIdx.x * 16;

    // ---- W fragments (B operand: B[k][n]=W[n][k]; lane n=32w+16t4+l, k=32c+8q+j) ----
    bf16x8 wf[8][2];
#pragma unroll
    for (int t4 = 0; t4 < 2; t4++) {
        const float* wr = W + (32 * wave + 16 * t4 + l) * D_DIM;
#pragma unroll
        for (int c = 0; c < 8; c++) {
            int k0 = 32 * c + 8 * q;
            float4 w0 = *(const float4*)(wr + k0);
            float4 w1 = *(const float4*)(wr + k0 + 4);
            bf16x8 f;
            f[0] = (__bf16)w0.x; f[1] = (__bf16)w0.y; f[2] = (__bf16)w0.z; f[3] = (__bf16)w0.w;
            f[4] = (__bf16)w1.x; f[5] = (__bf16)w1.y; f[6] = (__bf16)w1.z; f[7] = (__bf16)w1.w;
            wf[c][t4] = f;
        }
    }
    float bias[2];
#pragma unroll
    for (int t4 = 0; t4 < 2; t4++) bias[t4] = b[32 * wave + 16 * t4 + l];

    // quad q owns C/D rows 4q+r -> nodes perm[node0+4q+r]
    int base4[4], cnt4[4];
#pragma unroll
    for (int r = 0; r < 4; r++) {
        int n = perm[node0 + 4 * q + r];
        base4[r] = n << 6;
        cnt4[r] = min(counts[n], 64);
    }
    int S = min(counts[perm[node0]], 64);  // count-desc: first node = block max

    float h[2][4];
#pragma unroll
    for (int t4 = 0; t4 < 2; t4++)
#pragma unroll
        for (int r = 0; r < 4; r++) h[t4][r] = 0.f;

    // ---- prologue: x_0 = m_0 -> xA[0]; mvA = m_1; sidp = sid(m_2) ----
    float mvA[4][2], mvB[4][2];
    int sidp[4];
#pragma unroll
    for (int r = 0; r < 4; r++) {
        int s0 = spad[base4[r]];      // rows 0..2 always exist; >=cnt are 0 (memset)
        int s1 = spad[base4[r] + 1];
        const float* m0 = msg + (long)s0 * D_DIM;
        const float* m1 = msg + (long)s1 * D_DIM;
#pragma unroll
        for (int t4 = 0; t4 < 2; t4++) {
            int col = 32 * wave + 16 * t4 + l;
            xA[0][(4 * q + r) * XA_STRIDE + col] = (__bf16)m0[col];
            mvA[r][t4] = m1[col];
        }
        sidp[r] = spad[base4[r] + 2];
    }
    BAR();

    // one step: consume cur (=m_{s+1}) in epilogue, prefetch m_{s+2} into nxt
    auto step = [&](int s, float (&cur)[4][2], float (&nxt)[4][2]) {
        // prefetch m_{s+2} (register loads — survive the lgkm-only barrier)
#pragma unroll
        for (int r = 0; r < 4; r++) {
            const float* mrow = msg + (long)sidp[r] * D_DIM;
#pragma unroll
            for (int t4 = 0; t4 < 2; t4++) nxt[r][t4] = mrow[32 * wave + 16 * t4 + l];
        }
#pragma unroll
        for (int r = 0; r < 4; r++)
            sidp[r] = spad[base4[r] + min(s + 3, 63)];

        // MFMA: acc = x_s @ W^T
        const __bf16* buf = xA[s & 1];
        f32x4 acc[2];
#pragma unroll
        for (int t4 = 0; t4 < 2; t4++) acc[t4] = (f32x4){0.f, 0.f, 0.f, 0.f};
#pragma unroll
        for (int c = 0; c < 8; c++) {
            bf16x8 a = *(const bf16x8*)(buf + l * XA_STRIDE + 32 * c + 8 * q);
#pragma unroll
            for (int t4 = 0; t4 < 2; t4++)
                acc[t4] = __builtin_amdgcn_mfma_f32_16x16x32_bf16(a, wf[c][t4], acc[t4], 0, 0, 0);
        }

        // epilogue: h update (masked) + x_{s+1} = h + m_{s+1}
        __bf16* nbuf = xA[(s + 1) & 1];
#pragma unroll
        for (int t4 = 0; t4 < 2; t4++) {
#pragma unroll
            for (int r = 0; r < 4; r++) {
                float hn = acc[t4][r] + bias[t4];
                bool valid = s < cnt4[r];
                h[t4][r] = valid ? hn : h[t4][r];
                nbuf[(4 * q + r) * XA_STRIDE + 32 * wave + 16 * t4 + l] =
                    (__bf16)(h[t4][r] + cur[r][t4]);
            }
        }
        BAR();
    };

    int s = 0;
    while (s < S) {
        step(s, mvA, mvB);
        s++;
        if (s >= S) break;
        step(s, mvB, mvA);
        s++;
    }

    // ---- write fp32 h (0 for empty nodes) ----
#pragma unroll
    for (int r = 0; r < 4; r++) {
        int n = perm[node0 + 4 * q + r];  // reload (saves live regs in the loop)
#pragma unroll
        for (int t4 = 0; t4 < 2; t4++)
            out[(long)n * D_DIM + 32 * wave + 16 * t4 + l] = h[t4][r];
    }
}

// ================= launch =================

extern "C" void kernel_launch(void* const* d_in, const int* in_sizes, int n_in,
                              void* d_out, int out_size, void* d_ws, size_t ws_size,
                              hipStream_t stream) {
    const float* msg   = (const float*)d_in[0];
    const int*   index = (const int*)d_in[1];
    const float* t     = (const float*)d_in[2];
    const float* W     = (const float*)d_in[4];
    const float* b     = (const float*)d_in[5];
    float* out = (float*)d_out;

    int* ws = (int*)d_ws;
    int* cursors = ws;            // [8192] -> ends as counts
    int* pad     = ws + 8192;     // [8192*64] (contiguous with cursors for one memset)
    int* perm    = ws + 8192 + 8192 * 64;  // [8192]

    // zero cursors + pad in one memset (pad zeros make rows >= cnt safe)
    hipMemsetAsync(cursors, 0, (8192 + 8192 * 64) * sizeof(int), stream);

    k_scatter<<<E_MSGS / 256, 256, 0, stream>>>(index, cursors, pad);
    k_perm<<<1, 256, 0, stream>>>(cursors, perm);
    k_sortseg<<<N_NODES * 64 / 256, 256, 0, stream>>>(t, cursors, pad);
    k_gru<<<N_NODES / 16, 512, 0, stream>>>(msg, W, b, cursors, pad, perm, out);
}